// Round 4
// baseline (282.164 us; speedup 1.0000x reference)
//
#include <hip/hip_runtime.h>
#include <hip/hip_bf16.h>
#include <math.h>

// S4DConv via MFMA: B=8, L=2048, H=512, N=64, CH=1
//   k[h,t] rows appended to u rows -> A' [4608][2048]                [k_trans/k_kgen]
//   U'[4608][4096] = A' x [T1cos;T1sin]^T  (single GEMM, m97-style)  [k_fwd]
//   Ys = c_j/4096 * (KF * U) complex  (KF = U' rows 4096+h)          [k_mix]
//   y^T[bh,t] = Ys x T2 (K=4096), BK=64, LDS-transposed epilogue     [k_inv]

namespace {
constexpr int cB = 8;
constexpr int cL = 2048;
constexpr int cH = 512;
constexpr int cN = 64;
constexpr int M1 = 4095;
constexpr int M2 = 4096;
constexpr int BH = cB * cH;            // 4096
constexpr int MA = BH + cH;            // 4608 A' rows (u rows + k rows)

// float region
constexpr size_t WS_MODES = 0;                        // [H][N][6]: Cs_re,Cs_im,z_re,z_im,ar,ai
// short regions (ws viewed as short*)
constexpr size_t S0   = 2 * ((size_t)cH * cN * 6);    // 16B-aligned
constexpr size_t S_B1 = S0;                           // [4096][2048]: row j = cos(2pi jt/4095), row 2048+j = sin
constexpr size_t S_A  = S_B1 + (size_t)4096 * 2048;   // [4608][2048]
constexpr size_t S_T2 = S_A  + (size_t)MA * 2048;     // [2048][4096]: [t][j]=cos(2pi tj/4096), [t][2048+j]=sin
constexpr size_t S_U  = S_T2 + (size_t)2048 * 4096;   // [4608][4096]
constexpr size_t S_YS = S0;                           // overlay [4096][4096] (B1+A dead by then)
}

typedef __attribute__((ext_vector_type(8))) short short8;
typedef __attribute__((ext_vector_type(4))) float f32x4;

static __device__ inline short f2bf(float x) {
    __hip_bfloat16 h = __float2bfloat16(x);
    return *reinterpret_cast<short*>(&h);
}
static __device__ inline float bf2f(short s) {
    return __uint_as_float(((unsigned int)(unsigned short)s) << 16);
}
static __device__ __forceinline__ void load_lds16(const short* g, short* l) {
    __builtin_amdgcn_global_load_lds(
        (const __attribute__((address_space(1))) void*)g,
        (__attribute__((address_space(3))) void*)l, 16, 0, 0);
}

__global__ __launch_bounds__(256) void k_precomp(
    const float* __restrict__ w_re, const float* __restrict__ w_im,
    const float* __restrict__ C_re, const float* __restrict__ C_im,
    const float* __restrict__ dt, float* __restrict__ W)
{
    int idx = blockIdx.x * 256 + threadIdx.x;
    if (idx >= cH * cN) return;
    int h = idx / cN;
    double dtv = dt[h];
    double wr = w_re[idx], wi = w_im[idx];
    double ar = wr * dtv, ai = wi * dtv;
    double er = exp(ar);
    double zs, zc; sincos(ai, &zs, &zc);
    double zr = er * zc, zi = er * zs;
    double nr = zr - 1.0, ni = zi;
    double inv = 1.0 / (wr * wr + wi * wi);
    double gr = (nr * wr + ni * wi) * inv;
    double gi = (ni * wr - nr * wi) * inv;
    double cr = C_re[idx], ci = C_im[idx];
    double csr = cr * gr - ci * gi, csi = cr * gi + ci * gr;
    float* m = W + WS_MODES + (size_t)idx * 6;
    m[0] = (float)csr; m[1] = (float)csi;
    m[2] = (float)zr;  m[3] = (float)zi;
    m[4] = (float)ar;  m[5] = (float)ai;
}

// B1 rows: j -> cos(2pi jt/4095), 2048+j -> sin(2pi jt/4095)
__global__ __launch_bounds__(256) void k_tab1(short* __restrict__ Wb)
{
    int g = blockIdx.x * 256 + threadIdx.x;   // 2048*2048
    int j = g >> 11, t = g & 2047;
    int p = (j * t) % M1;
    float s, c;
    sincosf((6.283185307179586f / (float)M1) * (float)p, &s, &c);
    Wb[S_B1 + (size_t)j * 2048 + t]          = f2bf(c);
    Wb[S_B1 + (size_t)(2048 + j) * 2048 + t] = f2bf(s);
}

// T2[t][j]=cos(2pi*tj/4096), T2[t][2048+j]=sin(2pi*tj/4096)
__global__ __launch_bounds__(256) void k_tab2(short* __restrict__ Wb)
{
    int g = blockIdx.x * 256 + threadIdx.x;   // 2048*2048
    int t = g >> 11, j = g & 2047;
    int p = (t * j) & (M2 - 1);
    float s, c;
    sincosf((6.283185307179586f / (float)M2) * (float)p, &s, &c);
    Wb[S_T2 + (size_t)t * 4096 + j]        = f2bf(c);
    Wb[S_T2 + (size_t)t * 4096 + 2048 + j] = f2bf(s);
}

// A'[b*512+h][t] = bf16(u[b][t][h])
__global__ __launch_bounds__(256) void k_trans(const float* __restrict__ u,
                                               short* __restrict__ Wb)
{
    __shared__ float tile[64][65];
    int t0 = blockIdx.x * 64;
    int h0 = blockIdx.y * 64;
    int b  = blockIdx.z;
    int cx = threadIdx.x & 63, r0 = threadIdx.x >> 6;
#pragma unroll
    for (int i = 0; i < 16; ++i) {
        int row = r0 + i * 4;
        tile[row][cx] = u[((size_t)b * cL + t0 + row) * cH + h0 + cx];
    }
    __syncthreads();
    short* A = Wb + S_A;
#pragma unroll
    for (int i = 0; i < 16; ++i) {
        int hrow = r0 + i * 4;
        A[(size_t)(b * cH + h0 + hrow) * 2048 + t0 + cx] = f2bf(tile[cx][hrow]);
    }
}

// A'[4096+h][t] = bf16(k[h][t]) = 2 Re(sum_n Cs z^t)
__global__ __launch_bounds__(256) void k_kgen(const float* __restrict__ Wf,
                                              short* __restrict__ Wb)
{
    __shared__ float md[cN * 6];
    int h = blockIdx.x, tid = threadIdx.x;
    for (int i = tid; i < cN * 6; i += 256)
        md[i] = Wf[WS_MODES + (size_t)h * cN * 6 + i];
    __syncthreads();
    int t0 = tid * 8;
    float acc[8] = {0.f, 0.f, 0.f, 0.f, 0.f, 0.f, 0.f, 0.f};
    for (int n = 0; n < cN; ++n) {
        float csr = md[n*6+0], csi = md[n*6+1];
        float zr  = md[n*6+2], zi  = md[n*6+3];
        float ar  = md[n*6+4], ai  = md[n*6+5];
        float mag = expf(ar * (float)t0);
        double ph = fmod((double)ai * (double)t0, 6.283185307179586);
        float s, c; sincosf((float)ph, &s, &c);
        float pr = mag * c, pi = mag * s;
#pragma unroll
        for (int i = 0; i < 8; ++i) {
            acc[i] += csr * pr - csi * pi;
            float tr = pr * zr - pi * zi;
            pi = pr * zi + pi * zr;
            pr = tr;
        }
    }
    short8 v;
#pragma unroll
    for (int i = 0; i < 8; ++i) v[i] = f2bf(2.f * acc[i]);
    *reinterpret_cast<short8*>(&Wb[S_A + (size_t)(BH + h) * 2048 + t0]) = v;
}

// forward GEMM: U'[4608][4096] = A' x B1^T; 128x128 tile, BK=32, XCD swizzle
__global__ __launch_bounds__(256, 2) void k_fwd(short* __restrict__ Wb)
{
    __shared__ __align__(16) short As[128][32];
    __shared__ __align__(16) short Bs[128][32];
    const short* A = Wb + S_A;
    const short* B = Wb + S_B1;
    short* U = Wb + S_U;
    const int tid = threadIdx.x;
    // XCD-aware swizzle: 1152 blocks, 8 XCDs, 144 per XCD
    int tile = (blockIdx.x & 7) * 144 + (blockIdx.x >> 3);
    const int m0 = (tile >> 5) * 128, n0 = (tile & 31) * 128;
    const int wave = tid >> 6, lane = tid & 63;
    const int wr = wave >> 1, wc = wave & 1;
    const int lm = lane & 15, lk = lane >> 4;
    const int srow = lane >> 2, scol = (lane & 3) * 8;

    f32x4 acc[4][4] = {};

    for (int k0 = 0; k0 < 2048; k0 += 32) {
        __syncthreads();
        {
            int c0 = wave * 2;
            load_lds16(&A[(size_t)(m0 + c0*16      + srow)*2048 + k0 + scol], &As[c0*16][0]);
            load_lds16(&A[(size_t)(m0 + c0*16 + 16 + srow)*2048 + k0 + scol], &As[c0*16+16][0]);
            load_lds16(&B[(size_t)(n0 + c0*16      + srow)*2048 + k0 + scol], &Bs[c0*16][0]);
            load_lds16(&B[(size_t)(n0 + c0*16 + 16 + srow)*2048 + k0 + scol], &Bs[c0*16+16][0]);
        }
        __syncthreads();
        short8 a[4];
#pragma unroll
        for (int mi = 0; mi < 4; ++mi)
            a[mi] = *(const short8*)&As[wr*64 + mi*16 + lm][lk*8];
#pragma unroll
        for (int ni = 0; ni < 4; ++ni) {
            short8 b = *(const short8*)&Bs[wc*64 + ni*16 + lm][lk*8];
#pragma unroll
            for (int mi = 0; mi < 4; ++mi)
                acc[mi][ni] = __builtin_amdgcn_mfma_f32_16x16x32_bf16(a[mi], b, acc[mi][ni], 0, 0, 0);
        }
    }

#pragma unroll
    for (int mi = 0; mi < 4; ++mi)
#pragma unroll
    for (int ni = 0; ni < 4; ++ni)
#pragma unroll
    for (int r = 0; r < 4; ++r) {
        int row = m0 + wr*64 + mi*16 + lk*4 + r;
        int col = n0 + wc*64 + ni*16 + lm;
        U[(size_t)row * 4096 + col] = f2bf(acc[mi][ni][r]);
    }
}

// Ys[bh][j] = s*(Ck*C - Sk*S); Ys[bh][2048+j] = s*(Ck*S + Sk*C); s = (j?2:1)/4096
__global__ __launch_bounds__(256) void k_mix(short* __restrict__ Wb)
{
    const short* U = Wb + S_U;
    short* Ys = Wb + S_YS;
    int bh = blockIdx.x;
    int h  = bh & (cH - 1);
    int j0 = threadIdx.x * 8;
    short8 c8  = *(const short8*)&U[(size_t)bh * 4096 + j0];
    short8 s8  = *(const short8*)&U[(size_t)bh * 4096 + 2048 + j0];
    short8 ck8 = *(const short8*)&U[(size_t)(BH + h) * 4096 + j0];
    short8 sk8 = *(const short8*)&U[(size_t)(BH + h) * 4096 + 2048 + j0];
    short8 yr, yi;
#pragma unroll
    for (int i = 0; i < 8; ++i) {
        float C  = bf2f(c8[i]),  S  = bf2f(s8[i]);
        float Ck = bf2f(ck8[i]), Sk = bf2f(sk8[i]);
        float sc = ((j0 + i) == 0 ? 1.0f : 2.0f) / (float)M2;
        yr[i] = f2bf(sc * (Ck * C - Sk * S));
        yi[i] = f2bf(sc * (Ck * S + Sk * C));
    }
    *(short8*)&Ys[(size_t)bh * 4096 + j0]        = yr;
    *(short8*)&Ys[(size_t)bh * 4096 + 2048 + j0] = yi;
}

// inverse GEMM: y[bh][t] = Ys x T2^T, K=4096, BK=64, LDS-transposed epilogue
__global__ __launch_bounds__(256, 2) void k_inv(const float* __restrict__ u,
                                                const float* __restrict__ Dp,
                                                const short* __restrict__ Wb,
                                                float* __restrict__ out)
{
    __shared__ __align__(16) char smem[64 * 132 * 4];   // 33792 B
    short (*As)[64] = (short(*)[64])smem;               // [128][64] = 16 KB
    short (*Bt)[64] = (short(*)[64])(smem + 16384);     // [128][64] = 16 KB
    float (*Ls)[132] = (float(*)[132])smem;             // epilogue alias [64][132]

    const short* Ys = Wb + S_YS;
    const short* T2 = Wb + S_T2;
    const int tid = threadIdx.x;
    // XCD-aware swizzle: 512 blocks, 64 per XCD
    int tile = (blockIdx.x & 7) * 64 + (blockIdx.x >> 3);
    const int m0 = (tile >> 4) * 128, n0 = (tile & 15) * 128;
    const int wave = tid >> 6, lane = tid & 63;
    const int wr = wave >> 1, wc = wave & 1;
    const int lm = lane & 15, lk = lane >> 4;
    const int srow = lane >> 3, scol = (lane & 7) * 8;

    f32x4 acc[4][4] = {};

    for (int k0 = 0; k0 < 4096; k0 += 64) {
        __syncthreads();
        {
            int c0 = wave * 4;
#pragma unroll
            for (int i = 0; i < 4; ++i) {
                load_lds16(&Ys[(size_t)(m0 + (c0+i)*8 + srow)*4096 + k0 + scol], &As[(c0+i)*8][0]);
                load_lds16(&T2[(size_t)(n0 + (c0+i)*8 + srow)*4096 + k0 + scol], &Bt[(c0+i)*8][0]);
            }
        }
        __syncthreads();
#pragma unroll
        for (int kk = 0; kk < 2; ++kk) {
            short8 a[4];
#pragma unroll
            for (int mi = 0; mi < 4; ++mi)
                a[mi] = *(const short8*)&As[wr*64 + mi*16 + lm][kk*32 + lk*8];
#pragma unroll
            for (int ni = 0; ni < 4; ++ni) {
                short8 b = *(const short8*)&Bt[wc*64 + ni*16 + lm][kk*32 + lk*8];
#pragma unroll
                for (int mi = 0; mi < 4; ++mi)
                    acc[mi][ni] = __builtin_amdgcn_mfma_f32_16x16x32_bf16(a[mi], b, acc[mi][ni], 0, 0, 0);
            }
        }
    }

    // epilogue: transpose through LDS, coalesced float4 stores (t-major rows, h contiguous)
    const int b  = m0 >> 9;
    const int h0 = m0 & (cH - 1);
    const int col4 = tid & 31;      // h float4 index
    const int tr0  = tid >> 5;      // 0..7
    const float4 d4 = *(const float4*)&Dp[h0 + col4 * 4];
#pragma unroll
    for (int half = 0; half < 2; ++half) {
        __syncthreads();
        if (wc == half) {
#pragma unroll
            for (int mi = 0; mi < 4; ++mi)
#pragma unroll
            for (int ni = 0; ni < 4; ++ni) {
                int trow = ni * 16 + lm;
                int hcol = wr * 64 + mi * 16 + lk * 4;
                *(float4*)&Ls[trow][hcol] = *(float4*)&acc[mi][ni];
            }
        }
        __syncthreads();
#pragma unroll
        for (int it = 0; it < 8; ++it) {
            int tl = tr0 + it * 8;
            int t  = n0 + half * 64 + tl;
            size_t gidx = ((size_t)b * cL + t) * cH + h0 + col4 * 4;
            float4 uv = *(const float4*)&u[gidx];
            float4 yv = *(const float4*)&Ls[tl][col4 * 4];
            yv.x += d4.x * uv.x;
            yv.y += d4.y * uv.y;
            yv.z += d4.z * uv.z;
            yv.w += d4.w * uv.w;
            *(float4*)&out[gidx] = yv;
        }
    }
}

extern "C" void kernel_launch(void* const* d_in, const int* in_sizes, int n_in,
                              void* d_out, int out_size, void* d_ws, size_t ws_size,
                              hipStream_t stream) {
    const float* u    = (const float*)d_in[0];
    const float* w_re = (const float*)d_in[1];
    const float* w_im = (const float*)d_in[2];
    const float* C_re = (const float*)d_in[3];
    const float* C_im = (const float*)d_in[4];
    const float* Dp   = (const float*)d_in[5];
    const float* dt   = (const float*)d_in[6];
    float* out = (float*)d_out;
    float* Wf  = (float*)d_ws;
    short* Wb  = (short*)d_ws;

    hipLaunchKernelGGL(k_precomp, dim3((cH * cN + 255) / 256), dim3(256), 0, stream,
                       w_re, w_im, C_re, C_im, dt, Wf);
    hipLaunchKernelGGL(k_tab1,  dim3((2048 * 2048) / 256), dim3(256), 0, stream, Wb);
    hipLaunchKernelGGL(k_tab2,  dim3((2048 * 2048) / 256), dim3(256), 0, stream, Wb);
    hipLaunchKernelGGL(k_trans, dim3(cL / 64, cH / 64, cB), dim3(256), 0, stream, u, Wb);
    hipLaunchKernelGGL(k_kgen,  dim3(cH), dim3(256), 0, stream, Wf, Wb);
    hipLaunchKernelGGL(k_fwd,   dim3(36 * 32), dim3(256), 0, stream, Wb);
    hipLaunchKernelGGL(k_mix,   dim3(BH), dim3(256), 0, stream, Wb);
    hipLaunchKernelGGL(k_inv,   dim3(32 * 16), dim3(256), 0, stream, u, Dp, Wb, out);
}